// Round 3
// baseline (598.153 us; speedup 1.0000x reference)
//
#include <hip/hip_runtime.h>
#include <hip/hip_cooperative_groups.h>
#include <cstdint>
#include <cstddef>

namespace cg = cooperative_groups;

#define F_IN  128
#define F_HID 64
#define F_OUT 40

#define BSH   9     // bucket = dst >> 9 (512 nodes/bucket)
#define NBMAX 256   // supports N <= 131072
#define CHUNK 4096  // edges per partition job

typedef __attribute__((ext_vector_type(8))) short short8;   // 8 bf16 = 4 VGPR
typedef __attribute__((ext_vector_type(4))) float f32x4;    // MFMA C/D

// bf16 <-> f32 helpers (RNE on pack; values are finite)
__device__ __forceinline__ unsigned short f2bf(float f) {
  unsigned u = __float_as_uint(f);
  u += 0x7fffu + ((u >> 16) & 1u);
  return (unsigned short)(u >> 16);
}
__device__ __forceinline__ float bf2f(unsigned short b) {
  return __uint_as_float((unsigned)b << 16);
}
__device__ __forceinline__ float bflo(unsigned u) { return __uint_as_float(u << 16); }
__device__ __forceinline__ float bfhi(unsigned u) { return __uint_as_float(u & 0xffff0000u); }
__device__ __forceinline__ unsigned packbf(float lo, float hi) {
  return (unsigned)f2bf(lo) | ((unsigned)f2bf(hi) << 16);
}

// ===========================================================================
// K1 (cooperative): front(pcount + gemm1 + w2s emit) -> scanA -> scanC ->
// partition -> build.  Phases separated by grid.sync(); jobs grid-strided.
// LDS: union, max 35 KB (partition) -> 4 blocks/CU with __launch_bounds__.
// ===========================================================================
__global__ __launch_bounds__(256, 4) void pre_k(
    const float* __restrict__ x, const float* __restrict__ W1,
    const float* __restrict__ W2, unsigned short* __restrict__ w2s,
    unsigned short* __restrict__ xw,
    const int* __restrict__ ei, int* __restrict__ counts,
    int* __restrict__ psum, unsigned* __restrict__ ebuf,
    int* __restrict__ row_ptr, int* __restrict__ csr,
    int N, int E, int NBLK, int NBUCK, int M, int scanBlocks,
    int frontJobs, int G) {
  __shared__ union {
    struct { unsigned short w1l[8192]; int lh[NBMAX]; } f;        // 17.4 KB
    struct { int sb[256]; int sm[256]; } s;                       //  2 KB
    struct { uint2 slots[CHUNK]; int scn[NBMAX]; int lcur[NBMAX];
             int gadj[NBMAX]; } p;                                // 35 KB
    struct { int hist[512]; int psc[256]; } b;                    //  3 KB
  } u;
  cg::grid_group grid = cg::this_grid();
  int t = threadIdx.x;
  int blk = blockIdx.x;

  // ---- preload W1 -> LDS in MFMA B-frag order (once per block) ----
  {
    int k = t >> 1, n0 = (t & 1) * 32;       // thread owns W1[k][n0..n0+32)
    const float4* wp = (const float4*)(W1 + k * F_HID + n0);
    float4 v[8];
#pragma unroll
    for (int uu = 0; uu < 8; ++uu) v[uu] = wp[uu];
#pragma unroll
    for (int uu = 0; uu < 32; ++uu) {
      int n = n0 + uu;
      float f = ((const float*)v)[uu];
      int idx = ((n >> 4) * 4 + (k >> 5)) * 512 +
                (((k >> 3) & 3) * 16 + (n & 15)) * 8 + (k & 7);
      u.f.w1l[idx] = f2bf(f);
    }
  }
  __syncthreads();

  // ---- phase F: pcount chunks (jobs 0..NBLK) + gemm1 tiles ----
  for (int j = blk; j < frontJobs; j += G) {
    if (j < NBLK) {
      u.f.lh[t] = 0;
      __syncthreads();
      int e0 = j * CHUNK;
      int n = min(CHUNK, E - e0);
      for (int i = t; i < n; i += 256)
        atomicAdd(&u.f.lh[((unsigned)ei[E + e0 + i]) >> BSH], 1);
      __syncthreads();
      if (t < NBUCK) counts[t * NBLK + j] = u.f.lh[t];
      if (j == 0) {
        // emit swizzled W2 (cols >= 40 zero) for GEMM2 in agg_k
        for (int i = t; i < 3072; i += 256) {
          int f = i >> 9, r = i & 511;
          int lane = r >> 3, jj = r & 7;
          int ct = f >> 1, ks = f & 1;
          int n2 = ct * 16 + (lane & 15);
          int k = ks * 32 + (lane >> 4) * 8 + jj;
          w2s[i] = (n2 < F_OUT) ? f2bf(W2[k * F_OUT + n2]) : (unsigned short)0;
        }
      }
      __syncthreads();
    } else {
      int gblk = j - NBLK;
      int lane = t & 63;
      int wid = gblk * 4 + (t >> 6);
      int row0 = wid * 16;
      if (row0 < N) {
        int m = lane & 15, q = lane >> 4;
        if (row0 + 16 <= N) {
          short8 b[16];
#pragma unroll
          for (int f = 0; f < 16; ++f)
            b[f] = *(const short8*)(u.f.w1l + f * 512 + lane * 8);
          short8 a[4];
#pragma unroll
          for (int ks = 0; ks < 4; ++ks) {
            const float* xp = x + (size_t)(row0 + m) * F_IN + ks * 32 + q * 8;
            float4 v0 = *(const float4*)xp;
            float4 v1 = *(const float4*)(xp + 4);
            short8 tt;
            tt[0] = (short)f2bf(v0.x); tt[1] = (short)f2bf(v0.y);
            tt[2] = (short)f2bf(v0.z); tt[3] = (short)f2bf(v0.w);
            tt[4] = (short)f2bf(v1.x); tt[5] = (short)f2bf(v1.y);
            tt[6] = (short)f2bf(v1.z); tt[7] = (short)f2bf(v1.w);
            a[ks] = tt;
          }
          f32x4 z = {0.f, 0.f, 0.f, 0.f};
          f32x4 acc[4] = {z, z, z, z};
#pragma unroll
          for (int ct = 0; ct < 4; ++ct)
#pragma unroll
            for (int ks = 0; ks < 4; ++ks)
              acc[ct] = __builtin_amdgcn_mfma_f32_16x16x32_bf16(
                  a[ks], b[ct * 4 + ks], acc[ct], 0, 0, 0);
#pragma unroll
          for (int ct = 0; ct < 4; ++ct)
#pragma unroll
            for (int r = 0; r < 4; ++r) {
              int row = row0 + q * 4 + r;           // D: col=lane&15, row=q*4+reg
              xw[(size_t)row * F_HID + ct * 16 + m] = f2bf(acc[ct][r]);
            }
        } else {
          for (int r = 0; r < 16 && row0 + r < N; ++r) {   // tail: col = lane
            const float* xr = x + (size_t)(row0 + r) * F_IN;
            float s = 0.f;
            for (int k = 0; k < F_IN; ++k)
              s = fmaf(xr[k], W1[k * F_HID + lane], s);
            xw[(size_t)(row0 + r) * F_HID + lane] = f2bf(s);
          }
        }
      }
    }
  }
  grid.sync();

  // ---- scanA: per-2048-chunk totals of counts -> psum ----
  for (int j = blk; j < scanBlocks; j += G) {
    int base = j * 2048 + t * 8;
    int s = 0;
#pragma unroll
    for (int q = 0; q < 8; ++q) if (base + q < M) s += counts[base + q];
#pragma unroll
    for (int off = 32; off; off >>= 1) s += __shfl_xor(s, off, 64);
    if ((t & 63) == 0) u.s.sb[t >> 6] = s;
    __syncthreads();
    if (t == 0) psum[j] = u.s.sb[0] + u.s.sb[1] + u.s.sb[2] + u.s.sb[3];
    __syncthreads();
  }
  grid.sync();

  // ---- scanC: exclusive scan of counts in place (redundant psum scan) ----
  for (int j = blk; j < scanBlocks; j += G) {
    int pv = (t < scanBlocks) ? psum[t] : 0;
    u.s.sb[t] = pv;
    __syncthreads();
    for (int off = 1; off < 256; off <<= 1) {
      int add = (t >= off) ? u.s.sb[t - off] : 0;
      __syncthreads();
      u.s.sb[t] += add;
      __syncthreads();
    }
    int blockBase = (j > 0) ? u.s.sb[j - 1] : 0;   // exclusive prefix of chunk j
    int base = j * 2048 + t * 8;
    int v[8];
    int s = 0;
#pragma unroll
    for (int q = 0; q < 8; ++q) {
      v[q] = (base + q < M) ? counts[base + q] : 0;
      s += v[q];
    }
    u.s.sm[t] = s;
    __syncthreads();
    for (int off = 1; off < 256; off <<= 1) {
      int add = (t >= off) ? u.s.sm[t - off] : 0;
      __syncthreads();
      u.s.sm[t] += add;
      __syncthreads();
    }
    int run = blockBase + u.s.sm[t] - s;
#pragma unroll
    for (int q = 0; q < 8; ++q) {
      if (base + q < M) counts[base + q] = run;
      run += v[q];
    }
    if (j == 0 && t == 0) counts[M] = E;   // sentinel
    __syncthreads();
  }
  grid.sync();

  // ---- partition: stable multisplit into bucket-major packed ebuf ----
  for (int j = blk; j < NBLK; j += G) {
    int e0 = j * CHUNK;
    int n = min(CHUNK, E - e0);
    int i0 = t * NBLK + j;
    int cnt = 0, base0 = 0;
    if (t < NBUCK) { base0 = counts[i0]; cnt = counts[i0 + 1] - base0; }
    u.p.scn[t] = cnt;
    __syncthreads();
    for (int off = 1; off < 256; off <<= 1) {
      int add = (t >= off) ? u.p.scn[t - off] : 0;
      __syncthreads();
      u.p.scn[t] += add;
      __syncthreads();
    }
    int excl = u.p.scn[t] - cnt;
    if (t < NBUCK) { u.p.lcur[t] = excl; u.p.gadj[t] = base0 - excl; }
    __syncthreads();
    for (int i = t; i < n; i += 256) {
      int sv = ei[e0 + i], d = ei[E + e0 + i];
      int pos = atomicAdd(&u.p.lcur[((unsigned)d) >> BSH], 1);
      u.p.slots[pos] = make_uint2((unsigned)sv, (unsigned)d);
    }
    __syncthreads();
    for (int i = t; i < n; i += 256) {
      uint2 sd = u.p.slots[i];
      unsigned pk = ((sd.y & 511u) << 17) | sd.x;
      ebuf[u.p.gadj[sd.y >> BSH] + i] = pk;
    }
    __syncthreads();
  }
  grid.sync();

  // ---- build: per-bucket CSR (row_ptr + csr) ----
  for (int j = blk; j < NBUCK; j += G) {
    int nodeBase = j << BSH;
    int S = counts[j * NBLK];
    int T = counts[(j + 1) * NBLK];
    u.b.hist[t] = 0; u.b.hist[t + 256] = 0;
    __syncthreads();
    for (int i = S + t; i < T; i += 256)
      atomicAdd(&u.b.hist[ebuf[i] >> 17], 1);
    __syncthreads();
    int v0 = u.b.hist[2 * t], v1 = u.b.hist[2 * t + 1];
    int pair = v0 + v1;
    u.b.psc[t] = pair;
    __syncthreads();
    for (int off = 1; off < 256; off <<= 1) {
      int add = (t >= off) ? u.b.psc[t - off] : 0;
      __syncthreads();
      u.b.psc[t] += add;
      __syncthreads();
    }
    int ep = u.b.psc[t] - pair;
    int e0v = ep, e1v = ep + v0;
    int node0 = nodeBase + 2 * t;
    if (node0 < N) row_ptr[node0] = S + e0v;
    if (node0 + 1 < N) row_ptr[node0 + 1] = S + e1v;
    if (j == 0 && t == 0) row_ptr[N] = E;
    u.b.hist[2 * t] = e0v; u.b.hist[2 * t + 1] = e1v;  // cursors
    __syncthreads();
    for (int i = S + t; i < T; i += 256) {
      unsigned v = ebuf[i];
      int pos = atomicAdd(&u.b.hist[v >> 17], 1);
      csr[S + pos] = (int)(v & 0x1FFFFu);
    }
    __syncthreads();
  }
}

// ===========================================================================
// K2 (cooperative): agg1+bias1+relu+GEMM2 -> grid.sync -> agg2+bias2+lsm.
// hw rows are 128-B aligned (stride F_HID=64 bf16); only cols 0..39 written/
// read -> exactly one cache line per edge gather.
// ===========================================================================
__global__ __launch_bounds__(256, 6) void agg_k(
    const unsigned short* __restrict__ xw, const int* __restrict__ row_ptr,
    const int* __restrict__ csr, const float* __restrict__ b1,
    const unsigned short* __restrict__ w2s, const float* __restrict__ W2,
    unsigned short* __restrict__ hw, const float* __restrict__ b2,
    float* __restrict__ out, int N, int aggJobs, int G) {
  __shared__ uint4 hsm[32][8];            // 4 KB, XOR-swizzled on part
  cg::grid_group grid = cg::this_grid();
  int t = threadIdx.x, blk = blockIdx.x;
  int wave = t >> 6, lane = t & 63;
  int part = lane & 7;

  // ---- phase A1: aggregation layer 1 + GEMM2 (32 rows per job) ----
  for (int j = blk; j < aggJobs; j += G) {
    int blockRow0 = j * 32;
    int row = blockRow0 + wave * 8 + (lane >> 3);
    bool live = row < N;
    int start = live ? row_ptr[row] : 0;
    int end   = live ? row_ptr[row + 1] : 0;

    float acc[8], bcc[8];
#pragma unroll
    for (int q = 0; q < 8; ++q) { acc[q] = 0.f; bcc[q] = 0.f; }

    int i = start;
    for (; i + 3 < end; i += 4) {
      int s0 = csr[i];
      int s1 = csr[i + 1];
      int s2 = csr[i + 2];
      int s3 = csr[i + 3];
      uint4 v0 = *(const uint4*)(xw + ((size_t)s0 << 6) + (part << 3));
      uint4 v1 = *(const uint4*)(xw + ((size_t)s1 << 6) + (part << 3));
      uint4 v2 = *(const uint4*)(xw + ((size_t)s2 << 6) + (part << 3));
      uint4 v3 = *(const uint4*)(xw + ((size_t)s3 << 6) + (part << 3));
      acc[0] += bflo(v0.x); acc[1] += bfhi(v0.x);
      acc[2] += bflo(v0.y); acc[3] += bfhi(v0.y);
      acc[4] += bflo(v0.z); acc[5] += bfhi(v0.z);
      acc[6] += bflo(v0.w); acc[7] += bfhi(v0.w);
      bcc[0] += bflo(v1.x); bcc[1] += bfhi(v1.x);
      bcc[2] += bflo(v1.y); bcc[3] += bfhi(v1.y);
      bcc[4] += bflo(v1.z); bcc[5] += bfhi(v1.z);
      bcc[6] += bflo(v1.w); bcc[7] += bfhi(v1.w);
      acc[0] += bflo(v2.x); acc[1] += bfhi(v2.x);
      acc[2] += bflo(v2.y); acc[3] += bfhi(v2.y);
      acc[4] += bflo(v2.z); acc[5] += bfhi(v2.z);
      acc[6] += bflo(v2.w); acc[7] += bfhi(v2.w);
      bcc[0] += bflo(v3.x); bcc[1] += bfhi(v3.x);
      bcc[2] += bflo(v3.y); bcc[3] += bfhi(v3.y);
      bcc[4] += bflo(v3.z); bcc[5] += bfhi(v3.z);
      bcc[6] += bflo(v3.w); bcc[7] += bfhi(v3.w);
    }
    for (; i < end; ++i) {
      int s = csr[i];
      uint4 v = *(const uint4*)(xw + ((size_t)s << 6) + (part << 3));
      acc[0] += bflo(v.x); acc[1] += bfhi(v.x);
      acc[2] += bflo(v.y); acc[3] += bfhi(v.y);
      acc[4] += bflo(v.z); acc[5] += bfhi(v.z);
      acc[6] += bflo(v.w); acc[7] += bfhi(v.w);
    }

    if (live) {
      int c0 = part << 3;
      float4 bA = *(const float4*)(b1 + c0);
      float4 bB = *(const float4*)(b1 + c0 + 4);
      float r0 = fmaxf(acc[0] + bcc[0] + bA.x, 0.f);
      float r1 = fmaxf(acc[1] + bcc[1] + bA.y, 0.f);
      float r2 = fmaxf(acc[2] + bcc[2] + bA.z, 0.f);
      float r3 = fmaxf(acc[3] + bcc[3] + bA.w, 0.f);
      float r4 = fmaxf(acc[4] + bcc[4] + bB.x, 0.f);
      float r5 = fmaxf(acc[5] + bcc[5] + bB.y, 0.f);
      float r6 = fmaxf(acc[6] + bcc[6] + bB.z, 0.f);
      float r7 = fmaxf(acc[7] + bcc[7] + bB.w, 0.f);
      uint4 o = make_uint4(packbf(r0, r1), packbf(r2, r3),
                           packbf(r4, r5), packbf(r6, r7));
      int lr = row - blockRow0;
      hsm[lr][part ^ (lr & 7)] = o;
    }
    __syncthreads();

    // ---- GEMM2: h[32][64] @ W2[64][40] -> hw (stride 64, cols 0..39) ----
    if (wave < 2) {
      int frow0 = blockRow0 + wave * 16;
      if (frow0 < N) {
        int m = lane & 15, q = lane >> 4;
        if (frow0 + 16 <= N) {
          short8 b[6];
#pragma unroll
          for (int f = 0; f < 6; ++f)
            b[f] = *(const short8*)(w2s + f * 512 + lane * 8);
          short8 a[2];
#pragma unroll
          for (int ks = 0; ks < 2; ++ks) {
            int lr = wave * 16 + m;
            int p = ks * 4 + q;
            a[ks] = *(const short8*)&hsm[lr][p ^ (lr & 7)];
          }
          f32x4 z = {0.f, 0.f, 0.f, 0.f};
          f32x4 acc2[3] = {z, z, z};
#pragma unroll
          for (int ct = 0; ct < 3; ++ct)
#pragma unroll
            for (int ks = 0; ks < 2; ++ks)
              acc2[ct] = __builtin_amdgcn_mfma_f32_16x16x32_bf16(
                  a[ks], b[ct * 2 + ks], acc2[ct], 0, 0, 0);
#pragma unroll
          for (int ct = 0; ct < 3; ++ct)
#pragma unroll
            for (int r = 0; r < 4; ++r) {
              int row2 = frow0 + q * 4 + r;
              int c = ct * 16 + m;
              if (c < F_OUT) hw[(size_t)row2 * F_HID + c] = f2bf(acc2[ct][r]);
            }
        } else {
          for (int r = 0; r < 16; ++r) {          // tail rows (N%16 != 0)
            int row2 = frow0 + r;
            if (row2 >= N) break;
            if (lane < F_OUT) {
              int lr = wave * 16 + r;
              float s = 0.f;
              for (int k = 0; k < F_HID; ++k) {
                const unsigned short* hp =
                    (const unsigned short*)&hsm[lr][(k >> 3) ^ (lr & 7)];
                s = fmaf(bf2f(hp[k & 7]), W2[k * F_OUT + lane], s);
              }
              hw[(size_t)row2 * F_HID + lane] = f2bf(s);
            }
          }
        }
      }
    }
    __syncthreads();   // protect hsm before next job
  }
  grid.sync();

  // ---- phase A2: aggregation layer 2 + bias2 + log_softmax ----
  for (int j = blk; j < aggJobs; j += G) {
    int wid = j * 4 + wave;
    int rowBase = wid * 8;
    if (rowBase < N) {
      int row = rowBase + (lane >> 3);
      bool live = row < N;
      bool ld = live && (part < 5);

      int start = live ? row_ptr[row] : 0;
      int end   = live ? row_ptr[row + 1] : 0;

      float acc[8], bcc[8];
#pragma unroll
      for (int q = 0; q < 8; ++q) { acc[q] = 0.f; bcc[q] = 0.f; }

      int i = start;
      for (; i + 3 < end; i += 4) {
        int s0 = csr[i];
        int s1 = csr[i + 1];
        int s2 = csr[i + 2];
        int s3 = csr[i + 3];
        if (ld) {
          uint4 v0 = *(const uint4*)(hw + ((size_t)s0 << 6) + (part << 3));
          uint4 v1 = *(const uint4*)(hw + ((size_t)s1 << 6) + (part << 3));
          uint4 v2 = *(const uint4*)(hw + ((size_t)s2 << 6) + (part << 3));
          uint4 v3 = *(const uint4*)(hw + ((size_t)s3 << 6) + (part << 3));
          acc[0] += bflo(v0.x); acc[1] += bfhi(v0.x);
          acc[2] += bflo(v0.y); acc[3] += bfhi(v0.y);
          acc[4] += bflo(v0.z); acc[5] += bfhi(v0.z);
          acc[6] += bflo(v0.w); acc[7] += bfhi(v0.w);
          bcc[0] += bflo(v1.x); bcc[1] += bfhi(v1.x);
          bcc[2] += bflo(v1.y); bcc[3] += bfhi(v1.y);
          bcc[4] += bflo(v1.z); bcc[5] += bfhi(v1.z);
          bcc[6] += bflo(v1.w); bcc[7] += bfhi(v1.w);
          acc[0] += bflo(v2.x); acc[1] += bfhi(v2.x);
          acc[2] += bflo(v2.y); acc[3] += bfhi(v2.y);
          acc[4] += bflo(v2.z); acc[5] += bfhi(v2.z);
          acc[6] += bflo(v2.w); acc[7] += bfhi(v2.w);
          bcc[0] += bflo(v3.x); bcc[1] += bfhi(v3.x);
          bcc[2] += bflo(v3.y); bcc[3] += bfhi(v3.y);
          bcc[4] += bflo(v3.z); bcc[5] += bfhi(v3.z);
          bcc[6] += bflo(v3.w); bcc[7] += bfhi(v3.w);
        }
      }
      for (; i < end; ++i) {
        int s = csr[i];
        if (ld) {
          uint4 v = *(const uint4*)(hw + ((size_t)s << 6) + (part << 3));
          acc[0] += bflo(v.x); acc[1] += bfhi(v.x);
          acc[2] += bflo(v.y); acc[3] += bfhi(v.y);
          acc[4] += bflo(v.z); acc[5] += bfhi(v.z);
          acc[6] += bflo(v.w); acc[7] += bfhi(v.w);
        }
      }

      float vj[8];
      float mx = -3.4e38f;
      if (ld) {
        int c0 = part << 3;
        float4 bA = *(const float4*)(b2 + c0);
        float4 bB = *(const float4*)(b2 + c0 + 4);
        vj[0] = acc[0] + bcc[0] + bA.x; vj[1] = acc[1] + bcc[1] + bA.y;
        vj[2] = acc[2] + bcc[2] + bA.z; vj[3] = acc[3] + bcc[3] + bA.w;
        vj[4] = acc[4] + bcc[4] + bB.x; vj[5] = acc[5] + bcc[5] + bB.y;
        vj[6] = acc[6] + bcc[6] + bB.z; vj[7] = acc[7] + bcc[7] + bB.w;
#pragma unroll
        for (int q = 0; q < 8; ++q) mx = fmaxf(mx, vj[q]);
      }
#pragma unroll
      for (int off = 1; off < 8; off <<= 1) mx = fmaxf(mx, __shfl_xor(mx, off, 64));
      float ex = 0.f;
      if (ld) {
#pragma unroll
        for (int q = 0; q < 8; ++q) ex += __expf(vj[q] - mx);
      }
#pragma unroll
      for (int off = 1; off < 8; off <<= 1) ex += __shfl_xor(ex, off, 64);
      float lse = __logf(ex) + mx;

      if (ld) {
        int c0 = part << 3;
        float* op = out + (size_t)row * F_OUT + c0;
        *(float4*)op = make_float4(vj[0] - lse, vj[1] - lse,
                                   vj[2] - lse, vj[3] - lse);
        *(float4*)(op + 4) = make_float4(vj[4] - lse, vj[5] - lse,
                                         vj[6] - lse, vj[7] - lse);
      }
    }
  }
}

// ---------------------------------------------------------------------------
// ws layout (≈33 MB):
//   regA : xw[N,64] bf16
//   regB : ebuf[E] u32 — reused as hw[N,64] bf16 (ebuf dead after build)
//   row_ptr : N+1 | csr : E | counts : M+1 | psum : 256 | w2s : 3072
// ---------------------------------------------------------------------------
extern "C" void kernel_launch(void* const* d_in, const int* in_sizes, int n_in,
                              void* d_out, int out_size, void* d_ws, size_t ws_size,
                              hipStream_t stream) {
  const float* x  = (const float*)d_in[0];
  const int*   ei = (const int*)d_in[1];
  const float* W1 = (const float*)d_in[2];
  const float* b1 = (const float*)d_in[3];
  const float* W2 = (const float*)d_in[4];
  const float* b2 = (const float*)d_in[5];

  int N = in_sizes[0] / F_IN;
  int E = in_sizes[1] / 2;

  char* base = (char*)d_ws;
  size_t szA = (size_t)N * F_HID * sizeof(unsigned short);
  size_t szEb = (size_t)E * sizeof(unsigned);
  size_t szHw = (size_t)N * F_HID * sizeof(unsigned short);
  size_t szB = (szEb > szHw) ? szEb : szHw;
  unsigned short* xw = (unsigned short*)base;
  char* regB = base + ((szA + 255) & ~(size_t)255);
  unsigned* ebuf       = (unsigned*)regB;
  unsigned short* hw   = (unsigned short*)regB;
  int* row_ptr = (int*)(regB + ((szB + 255) & ~(size_t)255));
  int* csr     = row_ptr + N + 1;
  int* counts  = csr + E;
  float* out = (float*)d_out;

  int NBLK  = (E + CHUNK - 1) / CHUNK;
  int NBUCK = (N + 511) >> BSH;
  int M = NBUCK * NBLK;
  int* psum = counts + M + 1;
  unsigned short* w2s =
      (unsigned short*)(((uintptr_t)(psum + 256) + 63) & ~(uintptr_t)63);
  int scanBlocks = (M + 2047) / 2048;
  int gemmGrid = (N + 63) / 64;
  int frontJobs = NBLK + gemmGrid;
  int aggJobs = (N + 31) / 32;

  static int cap1 = -1, cap2 = -1, ncu = 0;
  if (cap1 < 0) {
    hipDeviceProp_t prop;
    int dev = 0;
    (void)hipGetDevice(&dev);
    (void)hipGetDeviceProperties(&prop, dev);
    ncu = prop.multiProcessorCount;
    if (ncu <= 0) ncu = 256;
    if (hipOccupancyMaxActiveBlocksPerMultiprocessor(&cap1,
            reinterpret_cast<const void*>(pre_k), 256, 0) != hipSuccess ||
        cap1 < 1)
      cap1 = 2;   // 2 blocks/CU always resident (LDS 70K, 8 waves/CU)
    if (hipOccupancyMaxActiveBlocksPerMultiprocessor(&cap2,
            reinterpret_cast<const void*>(agg_k), 256, 0) != hipSuccess ||
        cap2 < 1)
      cap2 = 2;
  }
  int G1 = cap1 * ncu; if (G1 > frontJobs) G1 = frontJobs;
  int G2 = cap2 * ncu; if (G2 > aggJobs) G2 = aggJobs;

  void* a1[] = {(void*)&x, (void*)&W1, (void*)&W2, (void*)&w2s, (void*)&xw,
                (void*)&ei, (void*)&counts, (void*)&psum, (void*)&ebuf,
                (void*)&row_ptr, (void*)&csr,
                (void*)&N, (void*)&E, (void*)&NBLK, (void*)&NBUCK, (void*)&M,
                (void*)&scanBlocks, (void*)&frontJobs, (void*)&G1};
  (void)hipLaunchCooperativeKernel(reinterpret_cast<const void*>(pre_k),
                                   dim3(G1), dim3(256), a1, 0, stream);

  void* a2[] = {(void*)&xw, (void*)&row_ptr, (void*)&csr, (void*)&b1,
                (void*)&w2s, (void*)&W2, (void*)&hw, (void*)&b2,
                (void*)&out, (void*)&N, (void*)&aggJobs, (void*)&G2};
  (void)hipLaunchCooperativeKernel(reinterpret_cast<const void*>(agg_k),
                                   dim3(G2), dim3(256), a2, 0, stream);
}